// Round 4
// baseline (98.956 us; speedup 1.0000x reference)
//
#include <hip/hip_runtime.h>

// Softmax over last axis, rows=2048, cols=32000, fp32 in/out.
// Reference: e^x / sum(e^x), no max subtraction (inputs in [0,1)).
//
// Single-pass per row: 1024-thread block, each thread caches 32 exp() values
// in registers (8 x float4) -> input read once, output written once (524 MB).
// Nontemporal load/store (touch-once streams; bypass L2/L3).
// Grid = rows/8 = 256 blocks; each block processes 8 rows sequentially.
// Stores of row r are fire-and-forget and overlap row r+1's loads (no barrier
// between them); wsum is double-buffered by row parity so only ONE barrier per
// row is needed (a second barrier would drain vmcnt and re-serialize phases).

#define SM_THREADS 1024
#define SM_V 32000
#define SM_FULL 7             // 7 * 1024 = 7168 full-coverage float4 iters
#define SM_REM 832            // 8000 - 7168 remainder float4s
#define SM_ROWS_PER_BLOCK 8

typedef float f32x4 __attribute__((ext_vector_type(4)));

__global__ __launch_bounds__(SM_THREADS, 1)
void softmax_rowwise_kernel(const float* __restrict__ in,
                            float* __restrict__ out) {
    const int tid = threadIdx.x;
    const int wave = tid >> 6;
    const int lane = tid & 63;

    __shared__ float wsum[2][SM_THREADS / 64];

    const int row0 = blockIdx.x * SM_ROWS_PER_BLOCK;

    for (int r = 0; r < SM_ROWS_PER_BLOCK; ++r) {
        const size_t base = (size_t)(row0 + r) * SM_V;
        const f32x4* __restrict__ inrow  = reinterpret_cast<const f32x4*>(in + base);
        f32x4* __restrict__       outrow = reinterpret_cast<f32x4*>(out + base);

        f32x4 e[8];
        float lsum = 0.0f;

        #pragma unroll
        for (int k = 0; k < SM_FULL; ++k) {
            f32x4 x = __builtin_nontemporal_load(&inrow[tid + k * SM_THREADS]);
            f32x4 ev;
            ev.x = __expf(x.x);
            ev.y = __expf(x.y);
            ev.z = __expf(x.z);
            ev.w = __expf(x.w);
            e[k] = ev;
            lsum += (ev.x + ev.y) + (ev.z + ev.w);
        }
        if (tid < SM_REM) {
            f32x4 x = __builtin_nontemporal_load(&inrow[tid + SM_FULL * SM_THREADS]);
            f32x4 ev;
            ev.x = __expf(x.x);
            ev.y = __expf(x.y);
            ev.z = __expf(x.z);
            ev.w = __expf(x.w);
            e[7] = ev;
            lsum += (ev.x + ev.y) + (ev.z + ev.w);
        }

        // Wave-level (64-lane) shuffle reduction.
        #pragma unroll
        for (int off = 32; off > 0; off >>= 1)
            lsum += __shfl_down(lsum, off, 64);

        // Block-level reduction across 16 waves via LDS (double-buffered by
        // row parity: one barrier per row; row r+1's write goes to the other
        // buffer, and the barrier at row r+1 orders it against row r's reads).
        if (lane == 0) wsum[r & 1][wave] = lsum;
        __syncthreads();

        float total = 0.0f;
        #pragma unroll
        for (int i = 0; i < SM_THREADS / 64; ++i)
            total += wsum[r & 1][i];   // broadcast LDS reads: conflict-free

        const float inv = 1.0f / total;

        #pragma unroll
        for (int k = 0; k < SM_FULL; ++k) {
            f32x4 ev = e[k];
            f32x4 o;
            o.x = ev.x * inv;
            o.y = ev.y * inv;
            o.z = ev.z * inv;
            o.w = ev.w * inv;
            __builtin_nontemporal_store(o, &outrow[tid + k * SM_THREADS]);
        }
        if (tid < SM_REM) {
            f32x4 ev = e[7];
            f32x4 o;
            o.x = ev.x * inv;
            o.y = ev.y * inv;
            o.z = ev.z * inv;
            o.w = ev.w * inv;
            __builtin_nontemporal_store(o, &outrow[tid + SM_FULL * SM_THREADS]);
        }
        // No barrier here: stores fire-and-forget, next row's loads issue now.
    }
}

extern "C" void kernel_launch(void* const* d_in, const int* in_sizes, int n_in,
                              void* d_out, int out_size, void* d_ws, size_t ws_size,
                              hipStream_t stream) {
    (void)n_in; (void)d_ws; (void)ws_size; (void)out_size;
    const float* in = (const float*)d_in[0];
    float* out = (float*)d_out;
    const int rows = in_sizes[0] / SM_V;               // 2048
    const int blocks = rows / SM_ROWS_PER_BLOCK;       // 256
    softmax_rowwise_kernel<<<dim3(blocks), dim3(SM_THREADS), 0, stream>>>(in, out);
}

// Round 5
// 93.991 us; speedup vs baseline: 1.0528x; 1.0528x over previous
//
#include <hip/hip_runtime.h>

// Softmax over last axis, rows=2048, cols=32000, fp32 in/out.
// Reference: e^x / sum(e^x), no max subtraction (inputs in [0,1)).
//
// Single-pass per row; 256 blocks x 8 rows sequential, software-pipelined:
// per iteration, row r+1's nontemporal loads are issued BEFORE row r's
// nontemporal stores (vmcnt counts both; this order keeps the exp of row r+1
// from waiting on row r's store drain), so the read and write streams stay
// concurrently in flight across the whole kernel. One barrier per row
// (wsum parity-double-buffered); its conservative vmcnt(0) drain overlaps
// loads+stores rather than serializing them.

#define SM_THREADS 1024
#define SM_V 32000
#define SM_FULL 7             // 7 * 1024 = 7168 full-coverage float4 iters
#define SM_REM 832            // 8000 - 7168 remainder float4s
#define SM_RPB 8              // rows per block

typedef float f32x4 __attribute__((ext_vector_type(4)));

__device__ __forceinline__ void load_row(const float* __restrict__ in,
                                         size_t base, int tid, f32x4 x[8]) {
    const f32x4* __restrict__ inrow = reinterpret_cast<const f32x4*>(in + base);
    #pragma unroll
    for (int k = 0; k < SM_FULL; ++k)
        x[k] = __builtin_nontemporal_load(&inrow[tid + k * SM_THREADS]);
    if (tid < SM_REM)
        x[7] = __builtin_nontemporal_load(&inrow[tid + SM_FULL * SM_THREADS]);
}

__device__ __forceinline__ float exp_row(const f32x4 x[8], f32x4 e[8], int tid) {
    float lsum = 0.0f;
    #pragma unroll
    for (int k = 0; k < SM_FULL; ++k) {
        f32x4 ev;
        ev.x = __expf(x[k].x);
        ev.y = __expf(x[k].y);
        ev.z = __expf(x[k].z);
        ev.w = __expf(x[k].w);
        e[k] = ev;
        lsum += (ev.x + ev.y) + (ev.z + ev.w);
    }
    if (tid < SM_REM) {
        f32x4 ev;
        ev.x = __expf(x[7].x);
        ev.y = __expf(x[7].y);
        ev.z = __expf(x[7].z);
        ev.w = __expf(x[7].w);
        e[7] = ev;
        lsum += (ev.x + ev.y) + (ev.z + ev.w);
    }
    return lsum;
}

__device__ __forceinline__ void store_row(float* __restrict__ out, size_t base,
                                          int tid, const f32x4 e[8], float inv) {
    f32x4* __restrict__ outrow = reinterpret_cast<f32x4*>(out + base);
    #pragma unroll
    for (int k = 0; k < SM_FULL; ++k) {
        f32x4 o;
        o.x = e[k].x * inv;
        o.y = e[k].y * inv;
        o.z = e[k].z * inv;
        o.w = e[k].w * inv;
        __builtin_nontemporal_store(o, &outrow[tid + k * SM_THREADS]);
    }
    if (tid < SM_REM) {
        f32x4 o;
        o.x = e[7].x * inv;
        o.y = e[7].y * inv;
        o.z = e[7].z * inv;
        o.w = e[7].w * inv;
        __builtin_nontemporal_store(o, &outrow[tid + SM_FULL * SM_THREADS]);
    }
}

__global__ __launch_bounds__(SM_THREADS, 1)
void softmax_rowwise_kernel(const float* __restrict__ in,
                            float* __restrict__ out) {
    const int tid = threadIdx.x;
    const int wave = tid >> 6;
    const int lane = tid & 63;

    __shared__ float wsum[2][SM_THREADS / 64];

    const int row0 = blockIdx.x * SM_RPB;

    f32x4 x[8], e[8];

    // Prologue: row 0 of this block.
    load_row(in, (size_t)row0 * SM_V, tid, x);
    float lsum = exp_row(x, e, tid);

    #pragma unroll
    for (int off = 32; off > 0; off >>= 1)
        lsum += __shfl_down(lsum, off, 64);
    if (lane == 0) wsum[0][wave] = lsum;
    __syncthreads();
    float total = 0.0f;
    #pragma unroll
    for (int i = 0; i < SM_THREADS / 64; ++i)
        total += wsum[0][i];
    float inv = 1.0f / total;

    for (int r = 0; r < SM_RPB; ++r) {
        f32x4 xn[8];
        const bool more = (r + 1 < SM_RPB);

        // 1) Issue next row's loads FIRST (keeps exp(r+1) off the store drain).
        if (more)
            load_row(in, (size_t)(row0 + r + 1) * SM_V, tid, xn);

        // 2) Fire-and-forget stores of current row.
        store_row(out, (size_t)(row0 + r) * SM_V, tid, e, inv);

        // 3) Consume next row's loads, reduce, one barrier (parity-buffered).
        if (more) {
            lsum = exp_row(xn, e, tid);
            #pragma unroll
            for (int off = 32; off > 0; off >>= 1)
                lsum += __shfl_down(lsum, off, 64);
            const int p = (r + 1) & 1;
            if (lane == 0) wsum[p][wave] = lsum;
            __syncthreads();
            total = 0.0f;
            #pragma unroll
            for (int i = 0; i < SM_THREADS / 64; ++i)
                total += wsum[p][i];
            inv = 1.0f / total;
        }
    }
}

extern "C" void kernel_launch(void* const* d_in, const int* in_sizes, int n_in,
                              void* d_out, int out_size, void* d_ws, size_t ws_size,
                              hipStream_t stream) {
    (void)n_in; (void)d_ws; (void)ws_size; (void)out_size;
    const float* in = (const float*)d_in[0];
    float* out = (float*)d_out;
    const int rows = in_sizes[0] / SM_V;               // 2048
    const int blocks = rows / SM_RPB;                  // 256
    softmax_rowwise_kernel<<<dim3(blocks), dim3(SM_THREADS), 0, stream>>>(in, out);
}